// Round 3
// baseline (772.503 us; speedup 1.0000x reference)
//
#include <hip/hip_runtime.h>
#include <cstdint>

#define B_SZ 4
#define S_LEN 1024
#define DIM 4096
#define NH 32
#define KVH 8
#define HD 128
#define DQKV 6144  // 4096 Q + 1024 K + 1024 V

typedef __bf16 bf16x8 __attribute__((ext_vector_type(8)));
typedef float f32x4 __attribute__((ext_vector_type(4)));

__device__ __forceinline__ unsigned short f2bf(float f) {
  union { float f; uint32_t u; } v; v.f = f;
  uint32_t u = v.u;
  return (unsigned short)((u + 0x7fffu + ((u >> 16) & 1u)) >> 16);
}
__device__ __forceinline__ float bf2f(unsigned short h) {
  union { uint32_t u; float f; } v; v.u = ((uint32_t)h) << 16;
  return v.f;
}
__device__ __forceinline__ float ex2(float x) {
#if __has_builtin(__builtin_amdgcn_exp2f)
  return __builtin_amdgcn_exp2f(x);
#else
  return exp2f(x);
#endif
}

// async global->LDS, 16B per lane; LDS dest = wave-uniform base + lane*16
__device__ __forceinline__ void async16(void* lds, const void* g) {
  __builtin_amdgcn_global_load_lds(
      (const __attribute__((address_space(1))) void*)g,
      (__attribute__((address_space(3))) void*)lds, 16, 0, 0);
}

// ---------------- elementwise f32 -> bf16 ----------------
__global__ void cvt_x_kernel(const float* __restrict__ x, unsigned short* __restrict__ xb) {
  size_t i = ((size_t)blockIdx.x * 256 + threadIdx.x) * 4;
  float4 v = *(const float4*)(x + i);
  ushort4 o;
  o.x = f2bf(v.x); o.y = f2bf(v.y); o.z = f2bf(v.z); o.w = f2bf(v.w);
  *(ushort4*)(xb + i) = o;
}

// ---------------- weight transpose+convert: w (K x N f32) -> wt (N x K bf16, ld=4096) ----
__global__ void wtrans_kernel(const float* __restrict__ w, unsigned short* __restrict__ wt, int N) {
  __shared__ float tile[64][65];
  int n0 = blockIdx.x * 64, k0 = blockIdx.y * 64;
  int tx = threadIdx.x & 63, ty = threadIdx.x >> 6;
#pragma unroll
  for (int i = 0; i < 16; i++) {
    int k = ty + i * 4;
    tile[k][tx] = w[(size_t)(k0 + k) * N + n0 + tx];
  }
  __syncthreads();
  int c = threadIdx.x & 31, ny = threadIdx.x >> 5;
#pragma unroll
  for (int i = 0; i < 8; i++) {
    int n = ny + i * 8;
    ushort2 o;
    o.x = f2bf(tile[2 * c][n]);
    o.y = f2bf(tile[2 * c + 1][n]);
    *(ushort2*)(wt + (size_t)(n0 + n) * DIM + k0 + 2 * c) = o;
  }
}

// ---------------- GEMM: C(MxN) = A(MxK bf16) * Bt(NxK bf16)^T ----------------
// 8-phase m201-style schedule, K-SPLIT half-tiles for >=4-phase prefetch slack.
// 256x256 tile, BK=64, dbuf LDS 128 KiB, 8 waves (2M x 4N), per-wave 128x64 out.
// Half-tile = all 256 rows x one 32-elem k-half (16 KB, 2 async16/thread).
// Phases: p0 = m0-3*k0, p1 = m4-7*k0, p2 = m0-3*k1, p3 = m4-7*k1 (16 MFMA each).
//   -> k0 regions of buf[cur] globally dead after p1; k1 after p3.
// Stage map (iter t): p0: A-k1(t+1)+B-k1(t+1) -> buf^1 (region freed at end of t-1)
//                     p2: A-k0(t+2) -> buf     (freed after p1)
//                     p3: B-k0(t+2) -> buf     (freed after p1)
// Waits (steady): W_a = vmcnt(8) at p0 (guards k1(t), issued p0 of t-1: 4 phases old)
//                 W_b = vmcnt(8) at p3 (guards k0(t+1), issued p2/p3 of t-1: 5-6 old)
// Max 12 loads in flight/wave; never vmcnt(0) in steady state.
// LDS: per buf 32768 ush: A[k0|k1] at 0/8192, B[k0|k1] at 16384/24576.
// Half layout: slot s in [0,1024): row=s>>2, phys chunk=s&3; swizzle: logical
// chunk c = p ^ ((row>>1)&3) (involution, applied on global src + on ds_read).
// ds_read: 16 lanes -> 8 distinct 16B slots x 2 = 2-way = free (m136).
template <bool OUT_BF16>
__global__ __launch_bounds__(512, 2) void gemm256_kernel(
    const unsigned short* __restrict__ A, const unsigned short* __restrict__ Bt,
    void* __restrict__ Cout, int Kdim, int ldc) {
  __shared__ __align__(16) unsigned short sh[2 * 32768];
  const int tid = threadIdx.x;
  const int wave = tid >> 6, lane = tid & 63;
  // XCD-aware bijective block swizzle (grid size % 8 == 0 for both call sites)
  const int nbx = gridDim.x;
  const int nb = nbx * (int)gridDim.y;
  const int bid = (int)blockIdx.y * nbx + (int)blockIdx.x;
  const int sb = (bid & 7) * (nb >> 3) + (bid >> 3);
  const int m0 = (sb / nbx) * 256, n0 = (sb % nbx) * 256;

  // staging: thread covers slots tid and tid+512 of a half-tile.
  // row = slot>>2 (0..255), phys chunk = slot&3, logical chunk = phys ^ ((row>>1)&3).
  // (row+128 has same swizzle bits: 128>>1 = 64, 64&3 = 0.)
  const int r0 = tid >> 2;                          // 0..127
  const int cs = (tid & 3) ^ ((tid >> 3) & 3);
  const unsigned short* gA = A + (size_t)(m0 + r0) * Kdim + cs * 8;
  const unsigned short* gB = Bt + (size_t)(n0 + r0) * Kdim + cs * 8;
  const size_t row128 = (size_t)128 * Kdim;

  // compute-side fragment addressing (16x16x32: lane row = lane&15, k-chunk = lane>>4)
  const int wm = wave >> 2, wn = wave & 3;
  const int rl = lane & 15, lh4 = lane >> 4;
  const int pc = (lh4 ^ ((rl >> 1) & 3)) * 8;       // swizzled phys chunk (elems)
  const int arow = (wm * 128 + rl) * 32 + pc;       // + m*512 + kh*8192
  const int brow = (wn * 64 + rl) * 32 + pc;        // + n*512 + kh*8192 + 16384

  f32x4 acc[8][4] = {};
  bf16x8 af[4], bf[4];

#define STG(BUF, BASEL, GPTR, KOFF) do {                                   \
    unsigned short* d_ = sh + (BUF) * 32768 + (BASEL) + wave * 512;        \
    async16(d_, (GPTR) + (KOFF));                                          \
    async16(d_ + 4096, (GPTR) + row128 + (KOFF));                          \
  } while (0)

#define PH(MH, KH, READB, STAGE_STMT, WAIT_STMT) do {                      \
    const unsigned short* bA_ = buf + (KH) * 8192;                         \
    _Pragma("unroll") for (int i = 0; i < 4; i++)                          \
      af[i] = *(const bf16x8*)(bA_ + arow + ((MH) * 4 + i) * 512);         \
    if (READB) {                                                           \
      const unsigned short* bB_ = buf + 16384 + (KH) * 8192;               \
      _Pragma("unroll") for (int n = 0; n < 4; n++)                        \
        bf[n] = *(const bf16x8*)(bB_ + brow + n * 512);                    \
    }                                                                      \
    STAGE_STMT;                                                            \
    WAIT_STMT;                                                             \
    __builtin_amdgcn_s_barrier();                                          \
    __builtin_amdgcn_s_setprio(1);                                         \
    _Pragma("unroll") for (int i = 0; i < 4; i++)                          \
      _Pragma("unroll") for (int n = 0; n < 4; n++)                        \
        acc[(MH) * 4 + i][n] = __builtin_amdgcn_mfma_f32_16x16x32_bf16(    \
            af[i], bf[n], acc[(MH) * 4 + i][n], 0, 0, 0);                  \
    __builtin_amdgcn_s_setprio(0);                                         \
    __builtin_amdgcn_s_barrier();                                          \
  } while (0)

  const int NT = Kdim >> 6;
  // prologue: K-tile 0 all 4 halves -> buf0; k0(1) -> buf1. 12 loads; wait first 8.
  STG(0, 0, gA, 0);          // A-k0(0)
  STG(0, 8192, gA, 32);      // A-k1(0)
  STG(0, 16384, gB, 0);      // B-k0(0)
  STG(0, 24576, gB, 32);     // B-k1(0)
  STG(1, 0, gA, 64);         // A-k0(1)
  STG(1, 16384, gB, 64);     // B-k0(1)
  asm volatile("s_waitcnt vmcnt(4)" ::: "memory");
  __builtin_amdgcn_s_barrier();

  for (int t = 0; t < NT; ++t) {
    const unsigned short* buf = sh + (t & 1) * 32768;
    const int nbuf = (t & 1) ^ 1;
    const size_t kb = (size_t)t * 64;
    // p0: m0-3 x k0; stage k1(t+1) -> buf^1; W_a
    PH(0, 0, 1,
       if (t + 1 < NT) { STG(nbuf, 8192, gA, kb + 96); STG(nbuf, 24576, gB, kb + 96); },
       if (t + 1 < NT) { asm volatile("s_waitcnt vmcnt(8)" ::: "memory"); }
       else { asm volatile("s_waitcnt vmcnt(0)" ::: "memory"); });
    // p1: m4-7 x k0 (B k0 frags reused from regs)
    PH(1, 0, 0, , );
    // p2: m0-3 x k1; stage A-k0(t+2) -> buf
    PH(0, 1, 1,
       if (t + 2 < NT) { STG(t & 1, 0, gA, kb + 128); }, );
    // p3: m4-7 x k1; stage B-k0(t+2) -> buf; W_b
    PH(1, 1, 0,
       if (t + 2 < NT) { STG(t & 1, 16384, gB, kb + 128); },
       if (t + 2 < NT) { asm volatile("s_waitcnt vmcnt(8)" ::: "memory"); }
       else if (t + 1 < NT) { asm volatile("s_waitcnt vmcnt(4)" ::: "memory"); });
  }
#undef STG
#undef PH

  // 16x16 C/D layout: col = lane&15, row = (lane>>4)*4 + reg  [m89/m91]
#pragma unroll
  for (int m = 0; m < 8; m++)
#pragma unroll
    for (int n = 0; n < 4; n++)
#pragma unroll
      for (int reg = 0; reg < 4; reg++) {
        int row = m0 + wm * 128 + m * 16 + lh4 * 4 + reg;
        int col = n0 + wn * 64 + n * 16 + rl;
        float v = acc[m][n][reg];
        if (OUT_BF16)
          ((unsigned short*)Cout)[(size_t)row * ldc + col] = f2bf(v);
        else
          ((float*)Cout)[(size_t)row * ldc + col] = v;
      }
}

// ---------------- RoPE + relayout: qkv rows (token, DQKV) -> (B, H, S, HD) -------------
__global__ void rope_kernel(const unsigned short* __restrict__ src, const float* __restrict__ fc,
                            const float* __restrict__ fs, unsigned short* __restrict__ dst,
                            int nheads, int hshift, float scale) {
  int idx = blockIdx.x * 256 + threadIdx.x;
  int f4 = idx & 15;
  int rest = idx >> 4;
  int hh = rest & (nheads - 1);
  int t = rest >> hshift;
  int s = t & (S_LEN - 1);
  int b = t >> 10;
  union { uint4 v; unsigned short u[8]; } in, out;
  in.v = *(const uint4*)(src + (size_t)t * DQKV + hh * HD + f4 * 8);
  union { float4 v; float f[4]; } c4, s4;
  c4.v = *(const float4*)(fc + s * 64 + f4 * 4);
  s4.v = *(const float4*)(fs + s * 64 + f4 * 4);
#pragma unroll
  for (int j = 0; j < 4; j++) {
    float xr = bf2f(in.u[2 * j]), xi = bf2f(in.u[2 * j + 1]);
    float cc = c4.f[j], ss = s4.f[j];
    out.u[2 * j] = f2bf((xr * cc - xi * ss) * scale);
    out.u[2 * j + 1] = f2bf((xr * ss + xi * cc) * scale);
  }
  *(uint4*)(dst + ((size_t)(b * nheads + hh) * S_LEN + s) * HD + f4 * 8) = out.v;
}

// ---------------- V transpose: qkv V cols (token, kvh*HD+d) -> Vt (B,KVH,HD,S) ----------
__global__ void vtrans_kernel(const unsigned short* __restrict__ src, unsigned short* __restrict__ Vt) {
  __shared__ __align__(16) unsigned short tile[32][33];
  int s0 = blockIdx.x * 32, d0 = blockIdx.y * 32, bk = blockIdx.z;
  int tx = threadIdx.x & 31, ty = threadIdx.x >> 5;
#pragma unroll
  for (int i = 0; i < 4; i++) {
    int s = ty + i * 8;
    tile[s][tx] = src[(size_t)((bk >> 3) * S_LEN + s0 + s) * DQKV + (bk & 7) * HD + d0 + tx];
  }
  __syncthreads();
#pragma unroll
  for (int i = 0; i < 4; i++) {
    int d = ty + i * 8;
    Vt[((size_t)bk * HD + d0 + d) * S_LEN + s0 + tx] = tile[tx][d];
  }
}

// ---------------- flash attention (non-causal, full 1024 keys) ----------------
__global__ __launch_bounds__(256, 3) void attn_kernel(
    const unsigned short* __restrict__ Qb,  // (B,NH,S,HD)
    const unsigned short* __restrict__ Kb,  // (B,KVH,S,HD)
    const unsigned short* __restrict__ Vt,  // (B,KVH,HD,S)
    unsigned short* __restrict__ Ob) {      // (token, NH*HD)
  __shared__ __align__(16) unsigned short Kt[64][128];   // [key][d-chunks, xor-swizzled]
  __shared__ __align__(16) unsigned short Vl[128][64];   // [d][key-chunks, xor-swizzled]
  __shared__ __align__(16) unsigned short Pl[4][16][72]; // per-wave [q][key], padded
  const int tid = threadIdx.x, wave = tid >> 6, lane = tid & 63;
  const int qb = blockIdx.x, h = blockIdx.y, b = blockIdx.z;
  const int kvh = h >> 2;  // N_REP = 4
  const int lql = lane & 15, lqh = lane >> 4;
  const int qrow = qb * 64 + wave * 16;

  const unsigned short* Qp = Qb + ((size_t)(b * NH + h) * S_LEN + qrow + lql) * HD + lqh * 8;
  bf16x8 qf[4];
#pragma unroll
  for (int kd = 0; kd < 4; kd++) qf[kd] = *(const bf16x8*)(Qp + kd * 32);

  const unsigned short* Kp = Kb + (size_t)(b * KVH + kvh) * S_LEN * HD;
  const unsigned short* Vp = Vt + (size_t)(b * KVH + kvh) * HD * S_LEN;
  const int krow_in = lane >> 4;               // +0..3 within 4-row group
  const int kcol_sw = lane & 15;               // physical chunk
  const int vrow_in = lane >> 3;               // +0..7 within 8-row group
  const int vcol_off = ((lane & 7) ^ (lane >> 3)) * 8;

  float m_run[4], l_run[4];
  f32x4 Oacc[8] = {};
#pragma unroll
  for (int r = 0; r < 4; r++) { m_run[r] = -3.0e38f; l_run[r] = 0.0f; }

  for (int kt = 0; kt < S_LEN; kt += 64) {
    __syncthreads();
#pragma unroll
    for (int j = 0; j < 4; j++) {
      int rbase = wave * 16 + j * 4;
      int r = rbase + krow_in;
      async16(&Kt[rbase][0], Kp + (size_t)(kt + r) * HD + ((kcol_sw ^ (r & 7)) * 8));
    }
#pragma unroll
    for (int j = 0; j < 4; j++) {
      int dbase = wave * 32 + j * 8;
      int d = dbase + vrow_in;
      async16(&Vl[dbase][0], Vp + (size_t)d * S_LEN + kt + vcol_off);
    }
    __syncthreads();
    f32x4 sf[4] = {};
#pragma unroll
    for (int ni = 0; ni < 4; ni++) {
      const int ksw = lql & 7;
#pragma unroll
      for (int kd = 0; kd < 4; kd++) {
        bf16x8 kf = *(const bf16x8*)(&Kt[ni * 16 + lql][((kd * 4 + lqh) ^ ksw) * 8]);
        sf[ni] = __builtin_amdgcn_mfma_f32_16x16x32_bf16(qf[kd], kf, sf[ni], 0, 0, 0);
      }
    }
    float mnew[4], alpha[4], psum[4];
#pragma unroll
    for (int r = 0; r < 4; r++) {
      float v = fmaxf(fmaxf(sf[0][r], sf[1][r]), fmaxf(sf[2][r], sf[3][r]));
      v = fmaxf(v, __shfl_xor(v, 1));
      v = fmaxf(v, __shfl_xor(v, 2));
      v = fmaxf(v, __shfl_xor(v, 4));
      v = fmaxf(v, __shfl_xor(v, 8));
      mnew[r] = fmaxf(m_run[r], v);
      alpha[r] = ex2(m_run[r] - mnew[r]);
      m_run[r] = mnew[r];
      psum[r] = 0.0f;
    }
#pragma unroll
    for (int ni = 0; ni < 4; ni++)
#pragma unroll
      for (int r = 0; r < 4; r++) {
        float p = ex2(sf[ni][r] - mnew[r]);
        psum[r] += p;
        union { float f; uint32_t u; } pv; pv.f = p;
        Pl[wave][lqh * 4 + r][ni * 16 + lql] = (unsigned short)(pv.u >> 16);
      }
#pragma unroll
    for (int r = 0; r < 4; r++) {
      float v = psum[r];
      v += __shfl_xor(v, 1);
      v += __shfl_xor(v, 2);
      v += __shfl_xor(v, 4);
      v += __shfl_xor(v, 8);
      l_run[r] = l_run[r] * alpha[r] + v;
    }
#pragma unroll
    for (int ni = 0; ni < 8; ni++)
#pragma unroll
      for (int r = 0; r < 4; r++) Oacc[ni][r] *= alpha[r];
    bf16x8 pa[2];
#pragma unroll
    for (int ks = 0; ks < 2; ks++)
      pa[ks] = *(const bf16x8*)(&Pl[wave][lql][ks * 32 + lqh * 8]);
#pragma unroll
    for (int ni = 0; ni < 8; ni++) {
      const int ksw = lql & 7;
#pragma unroll
      for (int ks = 0; ks < 2; ks++) {
        bf16x8 vb = *(const bf16x8*)(&Vl[ni * 16 + lql][((ks * 4 + lqh) ^ ksw) * 8]);
        Oacc[ni] = __builtin_amdgcn_mfma_f32_16x16x32_bf16(pa[ks], vb, Oacc[ni], 0, 0, 0);
      }
    }
  }
#pragma unroll
  for (int r = 0; r < 4; r++) l_run[r] = 1.0f / l_run[r];
#pragma unroll
  for (int ni = 0; ni < 8; ni++)
#pragma unroll
    for (int r = 0; r < 4; r++) {
      int q = qrow + lqh * 4 + r;
      Ob[(size_t)(b * S_LEN + q) * DIM + h * HD + ni * 16 + lql] = f2bf(Oacc[ni][r] * l_run[r]);
    }
}

extern "C" void kernel_launch(void* const* d_in, const int* in_sizes, int n_in,
                              void* d_out, int out_size, void* d_ws, size_t ws_size,
                              hipStream_t stream) {
  (void)in_sizes; (void)n_in; (void)out_size; (void)ws_size;
  const float* x  = (const float*)d_in[0];
  const float* fc = (const float*)d_in[1];
  const float* fs = (const float*)d_in[2];
  const float* wq = (const float*)d_in[3];
  const float* wk = (const float*)d_in[4];
  const float* wv = (const float*)d_in[5];
  const float* wo = (const float*)d_in[6];
  float* out = (float*)d_out;
  char* ws = (char*)d_ws;

  const size_t MB = 1024 * 1024;
  unsigned short* xb    = (unsigned short*)(ws + 0);         // 32MB; dead after gemm1
  unsigned short* attnb = (unsigned short*)(ws + 0);         // reuses xb slot
  unsigned short* wqkvt = (unsigned short*)(ws + 32 * MB);   // 48MB; dead after gemm1
  unsigned short* Qb    = (unsigned short*)(ws + 32 * MB);   // 32MB, reuses wqkvt
  unsigned short* Kb    = (unsigned short*)(ws + 64 * MB);   // 8MB
  unsigned short* Vt    = (unsigned short*)(ws + 72 * MB);   // 8MB
  unsigned short* wot   = (unsigned short*)(ws + 80 * MB);   // 32MB
  unsigned short* qkv   = (unsigned short*)(ws + 112 * MB);  // 48MB

  cvt_x_kernel<<<16384, 256, 0, stream>>>(x, xb);
  wtrans_kernel<<<dim3(64, 64), 256, 0, stream>>>(wq, wqkvt, 4096);
  wtrans_kernel<<<dim3(16, 64), 256, 0, stream>>>(wk, wqkvt + (size_t)4096 * 4096, 1024);
  wtrans_kernel<<<dim3(16, 64), 256, 0, stream>>>(wv, wqkvt + (size_t)5120 * 4096, 1024);
  wtrans_kernel<<<dim3(64, 64), 256, 0, stream>>>(wo, wot, 4096);
  // QKV projection: (4096 x 4096) @ (4096 x 6144) -> bf16; grid 24x16=384 (%8==0)
  gemm256_kernel<true><<<dim3(DQKV / 256, 16), 512, 0, stream>>>(xb, wqkvt, qkv, DIM, DQKV);
  // RoPE + relayout; Q scale = (1/sqrt(128)) * log2(e) for log2-domain softmax
  rope_kernel<<<8192, 256, 0, stream>>>(qkv, fc, fs, Qb, NH, 5, 0.12751879505099168f);
  rope_kernel<<<2048, 256, 0, stream>>>(qkv + 4096, fc, fs, Kb, KVH, 3, 1.0f);
  vtrans_kernel<<<dim3(32, 4, 32), 256, 0, stream>>>(qkv + 5120, Vt);
  // attention
  attn_kernel<<<dim3(16, NH, B_SZ), 256, 0, stream>>>(Qb, Kb, Vt, attnb);
  // out projection: fp32 out; grid 16x16=256 (%8==0)
  gemm256_kernel<false><<<dim3(16, 16), 512, 0, stream>>>(attnb, wot, out, DIM, DIM);
}